// Round 3
// baseline (4139.531 us; speedup 1.0000x reference)
//
#include <hip/hip_runtime.h>
#include <math.h>

// ---------------------------------------------------------------------------
// TransformerXL forward — bf16 MFMA GEMMs + fused flash-style rel-attention.
// QLEN=512 MEM_LEN=512 KLEN=1024 BSZ=4 NH=16 DH=64 DM=1024 DI=4096 V=32000 L=6
// ---------------------------------------------------------------------------

typedef unsigned short u16;
typedef __attribute__((ext_vector_type(8))) short bf16x8;
typedef __attribute__((ext_vector_type(4))) float f32x4;

#define LINMOD (1 << 30)
constexpr int PITCH = 40;   // mgemm LDS row pitch (32 data + 8 pad)

__device__ __forceinline__ u16 f2bf(float f) {
    unsigned u = __float_as_uint(f);
    return (u16)((u + 0x7fffu + ((u >> 16) & 1u)) >> 16);
}
__device__ __forceinline__ float bf2f(u16 b) {
    return __uint_as_float((unsigned)b << 16);
}

// ---------------------------------------------------------------------------
// bf16 MFMA GEMM (tiles BM x BN, K multiple of 32). C = A[M,K] * B[N,K]^T.
// EPI: 0 = fp32 store (+bias,+relu), 1 = bf16 store (+bias,+relu),
//      2 = fused row-wise logsumexp partials: writes float2(max, sumexp)
//          per (row, col-block) to Cv[row * gridDim.x + colblk].
// Batched via blockIdx.z: off = (z%mod)*lo + (z/mod)*hi.
// swz: bijective XCD-chunk swizzle — each XCD gets contiguous col-blocks,
//      row-blocks iterate fastest within an XCD (B-tile reuse in per-XCD L2).
// ---------------------------------------------------------------------------
template<int BM, int BN, int EPI>
__global__ __launch_bounds__(256)
void mgemm(const u16* __restrict__ A, int lda, long alo, long ahi, int amod,
           const u16* __restrict__ B, int ldb, long blo, long bhi, int bmod,
           void* __restrict__ Cv, int ldc, long clo, long chi, int cmod,
           const float* __restrict__ bias, int M, int N, int K, int relu, int swz)
{
    constexpr int WM = BM / 2, WN = BN / 2, MT = WM / 16, NT = WN / 16;
    __shared__ u16 As[BM * PITCH];
    __shared__ u16 Bs[BN * PITCH];
    const int z = blockIdx.z;
    A += (long)(z % amod) * alo + (long)(z / amod) * ahi;
    B += (long)(z % bmod) * blo + (long)(z / bmod) * bhi;
    const long coff = (long)(z % cmod) * clo + (long)(z / cmod) * chi;

    int bx = blockIdx.x, by = blockIdx.y;
    if (swz) {
        int nwg = gridDim.x * gridDim.y;
        int flat = by * gridDim.x + bx;
        int q = nwg >> 3, rr = nwg & 7, xcd = flat & 7, idx = flat >> 3;
        int wgid = (xcd < rr ? xcd * (q + 1) : rr * (q + 1) + (xcd - rr) * q) + idx;
        by = wgid % gridDim.y;          // row-block fastest within XCD
        bx = wgid / gridDim.y;          // contiguous col-blocks per XCD
    }
    const int m0 = by * BM, n0 = bx * BN;
    const int t = threadIdx.x;
    const int l = t & 63, w = t >> 6;
    const int wm = w >> 1, wn = w & 1;
    const int fr = l & 15, fq = l >> 4;

    f32x4 acc[MT][NT];
    #pragma unroll
    for (int i = 0; i < MT; ++i)
        #pragma unroll
        for (int j = 0; j < NT; ++j) acc[i][j] = (f32x4){0.f, 0.f, 0.f, 0.f};

    constexpr int AIT = BM * 4 / 256;
    constexpr int BIT = BN * 4 / 256;

    const int nk = K / 32;
    for (int kt = 0; kt < nk; ++kt) {
        uint4 av[AIT], bv[BIT];
        #pragma unroll
        for (int i = 0; i < AIT; ++i) {
            int c = t + i * 256, row = c >> 2, q = c & 3;
            av[i] = *(const uint4*)(A + (long)(m0 + row) * lda + kt * 32 + q * 8);
        }
        #pragma unroll
        for (int i = 0; i < BIT; ++i) {
            int c = t + i * 256, row = c >> 2, q = c & 3;
            bv[i] = *(const uint4*)(B + (long)(n0 + row) * ldb + kt * 32 + q * 8);
        }
        __syncthreads();
        #pragma unroll
        for (int i = 0; i < AIT; ++i) {
            int c = t + i * 256, row = c >> 2, q = c & 3;
            *(uint4*)&As[row * PITCH + q * 8] = av[i];
        }
        #pragma unroll
        for (int i = 0; i < BIT; ++i) {
            int c = t + i * 256, row = c >> 2, q = c & 3;
            *(uint4*)&Bs[row * PITCH + q * 8] = bv[i];
        }
        __syncthreads();
        bf16x8 af[MT], bfr[NT];
        #pragma unroll
        for (int i = 0; i < MT; ++i)
            af[i] = *(const bf16x8*)&As[(wm * WM + i * 16 + fr) * PITCH + fq * 8];
        #pragma unroll
        for (int j = 0; j < NT; ++j)
            bfr[j] = *(const bf16x8*)&Bs[(wn * WN + j * 16 + fr) * PITCH + fq * 8];
        #pragma unroll
        for (int i = 0; i < MT; ++i)
            #pragma unroll
            for (int j = 0; j < NT; ++j)
                acc[i][j] = __builtin_amdgcn_mfma_f32_16x16x32_bf16(
                    af[i], bfr[j], acc[i][j], 0, 0, 0);
    }

    if constexpr (EPI == 1) {
        u16* C = (u16*)Cv + coff;
        #pragma unroll
        for (int i = 0; i < MT; ++i) {
            int rb = m0 + wm * WM + i * 16 + fq * 4;
            #pragma unroll
            for (int j = 0; j < NT; ++j) {
                int gcol = n0 + wn * WN + j * 16 + fr;
                float bb = bias ? bias[gcol] : 0.f;
                #pragma unroll
                for (int r = 0; r < 4; ++r) {
                    float v = acc[i][j][r] + bb;
                    if (relu) v = fmaxf(v, 0.f);
                    C[(long)(rb + r) * ldc + gcol] = f2bf(v);
                }
            }
        }
    } else if constexpr (EPI == 0) {
        float* C = (float*)Cv + coff;
        #pragma unroll
        for (int i = 0; i < MT; ++i) {
            int rb = m0 + wm * WM + i * 16 + fq * 4;
            #pragma unroll
            for (int j = 0; j < NT; ++j) {
                int gcol = n0 + wn * WN + j * 16 + fr;
                float bb = bias ? bias[gcol] : 0.f;
                #pragma unroll
                for (int r = 0; r < 4; ++r) {
                    float v = acc[i][j][r] + bb;
                    if (relu) v = fmaxf(v, 0.f);
                    C[(long)(rb + r) * ldc + gcol] = v;
                }
            }
        }
    } else {
        // EPI == 2: fused logsumexp — reduce the 128-wide tile to per-row
        // (max, sumexp) and write one float2 partial per row per col-block.
        __shared__ float pm[2][BM];
        __shared__ float ps[2][BM];
        float bb[NT];
        #pragma unroll
        for (int j = 0; j < NT; ++j)
            bb[j] = bias ? bias[n0 + wn * WN + j * 16 + fr] : 0.f;
        #pragma unroll
        for (int i = 0; i < MT; ++i) {
            #pragma unroll
            for (int r = 0; r < 4; ++r) {
                float mx = -3e38f;
                #pragma unroll
                for (int j = 0; j < NT; ++j) mx = fmaxf(mx, acc[i][j][r] + bb[j]);
                mx = fmaxf(mx, __shfl_xor(mx, 1, 64));
                mx = fmaxf(mx, __shfl_xor(mx, 2, 64));
                mx = fmaxf(mx, __shfl_xor(mx, 4, 64));
                mx = fmaxf(mx, __shfl_xor(mx, 8, 64));
                float s = 0.f;
                #pragma unroll
                for (int j = 0; j < NT; ++j) s += __expf(acc[i][j][r] + bb[j] - mx);
                s += __shfl_xor(s, 1, 64);
                s += __shfl_xor(s, 2, 64);
                s += __shfl_xor(s, 4, 64);
                s += __shfl_xor(s, 8, 64);
                if (fr == 0) {
                    int row = wm * WM + i * 16 + fq * 4 + r;
                    pm[wn][row] = mx;
                    ps[wn][row] = s;
                }
            }
        }
        __syncthreads();
        if (t < BM && (m0 + t) < M) {
            float ma = pm[0][t], mb = pm[1][t];
            float m = fmaxf(ma, mb);
            float s = ps[0][t] * __expf(ma - m) + ps[1][t] * __expf(mb - m);
            float2* P = (float2*)Cv;
            P[(long)(m0 + t) * gridDim.x + bx] = make_float2(m, s);
        }
    }
}

template<int BM, int BN, int EPI>
static inline void mg(hipStream_t st,
    const u16* A, int lda, long alo, long ahi, int amod,
    const u16* B, int ldb, long blo, long bhi, int bmod,
    void* C, int ldc, long clo, long chi, int cmod,
    const float* bias, int M, int N, int K, int relu, int batch, int swz)
{
    dim3 grid(N / BN, M / BM, batch);
    mgemm<BM, BN, EPI><<<grid, 256, 0, st>>>(A, lda, alo, ahi, amod,
        B, ldb, blo, bhi, bmod, C, ldc, clo, chi, cmod, bias, M, N, K, relu, swz);
}

// ---------------------------------------------------------------------------
// Fused rel-attention: per block (z = b*16+n, i-tile of 128 rows).
// AC = (q+rwb)K^T via MFMA; BD = (q+rrb)R^T computed per 128-wide jr-tile
// (rolling 2-slot LDS rotation, slot also reused for P); rel-shift applied
// when assembling the score; online softmax; PV accumulated in registers.
// ---------------------------------------------------------------------------
__global__ __launch_bounds__(256)
void attn_kernel(const u16* __restrict__ qw, const u16* __restrict__ qr,
                 const u16* __restrict__ heads, const u16* __restrict__ rbuf,
                 u16* __restrict__ attnv)
{
    __shared__ u16 sm[80384];
    __shared__ float pmax[2][128];
    __shared__ float psum[2][128];
    u16* qw_s = sm;             // 128x72
    u16* qr_s = sm + 9216;      // 128x72
    u16* k_s  = sm + 18432;     // 128x72
    u16* r_s  = sm + 27648;     // 128x72
    u16* vT_s = sm + 36864;     // 64x136 (V transposed)
    u16* bd0  = sm + 45568;     // 128x136 (BD/P rotating slots)
    u16* bd1  = sm + 62976;     // 128x136

    const int zz = blockIdx.x, b = zz >> 4, n = zz & 15;
    const int i0 = blockIdx.y * 128;
    const int t = threadIdx.x, l = t & 63, w = t >> 6;
    const int fr = l & 15, fq = l >> 4, wm = w >> 1, wn = w & 1;

    // ---- stage q tiles (persistent) + first r tile (jr0 = 384 - i0) ----
    const u16* qwg = qw + (long)zz * 32768 + (long)i0 * 64;
    const u16* qrg = qr + (long)zz * 32768 + (long)i0 * 64;
    {
        int jr0 = 384 - i0;
        #pragma unroll
        for (int it = 0; it < 4; ++it) {
            int idx = t + it * 256, row = idx >> 3, q8 = idx & 7;
            *(uint4*)&qw_s[row * 72 + q8 * 8] = *(const uint4*)&qwg[row * 64 + q8 * 8];
            *(uint4*)&qr_s[row * 72 + q8 * 8] = *(const uint4*)&qrg[row * 64 + q8 * 8];
            *(uint4*)&r_s[row * 72 + q8 * 8] =
                *(const uint4*)&rbuf[(long)(jr0 + row) * 1024 + n * 64 + q8 * 8];
        }
    }
    __syncthreads();

    // BD tile compute: (qr_s x r_s^T) -> bf16 LDS slot
    auto computeBD = [&](u16* out) {
        f32x4 bacc[4][4];
        #pragma unroll
        for (int i = 0; i < 4; ++i)
            #pragma unroll
            for (int j = 0; j < 4; ++j) bacc[i][j] = (f32x4){0.f, 0.f, 0.f, 0.f};
        #pragma unroll
        for (int ks = 0; ks < 2; ++ks) {
            bf16x8 af[4], bfr[4];
            #pragma unroll
            for (int i = 0; i < 4; ++i)
                af[i] = *(const bf16x8*)&qr_s[(wm * 64 + i * 16 + fr) * 72 + ks * 32 + fq * 8];
            #pragma unroll
            for (int j = 0; j < 4; ++j)
                bfr[j] = *(const bf16x8*)&r_s[(wn * 64 + j * 16 + fr) * 72 + ks * 32 + fq * 8];
            #pragma unroll
            for (int i = 0; i < 4; ++i)
                #pragma unroll
                for (int j = 0; j < 4; ++j)
                    bacc[i][j] = __builtin_amdgcn_mfma_f32_16x16x32_bf16(
                        af[i], bfr[j], bacc[i][j], 0, 0, 0);
        }
        #pragma unroll
        for (int i = 0; i < 4; ++i)
            #pragma unroll
            for (int j = 0; j < 4; ++j)
                #pragma unroll
                for (int r = 0; r < 4; ++r)
                    out[(wm * 64 + i * 16 + fq * 4 + r) * 136 + wn * 64 + j * 16 + fr] =
                        f2bf(bacc[i][j][r]);
    };
    computeBD(bd0);

    float m_st[4][4], l_st[4][4];
    #pragma unroll
    for (int i = 0; i < 4; ++i)
        #pragma unroll
        for (int r = 0; r < 4; ++r) { m_st[i][r] = -3e38f; l_st[i][r] = 0.f; }
    f32x4 Oa[4][2];
    #pragma unroll
    for (int i = 0; i < 4; ++i)
        #pragma unroll
        for (int j = 0; j < 2; ++j) Oa[i][j] = (f32x4){0.f, 0.f, 0.f, 0.f};

    const int ntiles = (640 + i0) >> 7;
    for (int tt = 0; tt < ntiles; ++tt) {
        const int j0 = tt << 7;
        const int jr0b = j0 - i0 + 512;
        u16* bda = (tt & 1) ? bd1 : bd0;
        u16* bdb = (tt & 1) ? bd0 : bd1;

        __syncthreads();   // protect k/r/vT/P from previous iteration's readers

        // ---- stage k, vT (transposed), next r ----
        #pragma unroll
        for (int it = 0; it < 4; ++it) {
            int idx = t + it * 256, row = idx >> 3, q8 = idx & 7;
            long hb = ((long)(j0 + row) * 4 + b) * 3072 + n * 64 + q8 * 8;
            *(uint4*)&k_s[row * 72 + q8 * 8] = *(const uint4*)&heads[hb + 1024];
            uint4 vv = *(const uint4*)&heads[hb + 2048];
            u16 vt[8]; *(uint4*)vt = vv;
            #pragma unroll
            for (int d = 0; d < 8; ++d) vT_s[(q8 * 8 + d) * 136 + row] = vt[d];
            if (jr0b < 1024)
                *(uint4*)&r_s[row * 72 + q8 * 8] =
                    *(const uint4*)&rbuf[(long)(jr0b + row) * 1024 + n * 64 + q8 * 8];
        }
        __syncthreads();

        // ---- BD for next jr tile ----
        if (jr0b < 1024) computeBD(bdb);

        // ---- AC MFMA ----
        f32x4 acc[4][4];
        #pragma unroll
        for (int i = 0; i < 4; ++i)
            #pragma unroll
            for (int j = 0; j < 4; ++j) acc[i][j] = (f32x4){0.f, 0.f, 0.f, 0.f};
        #pragma unroll
        for (int ks = 0; ks < 2; ++ks) {
            bf16x8 af[4], bfr[4];
            #pragma unroll
            for (int i = 0; i < 4; ++i)
                af[i] = *(const bf16x8*)&qw_s[(wm * 64 + i * 16 + fr) * 72 + ks * 32 + fq * 8];
            #pragma unroll
            for (int j = 0; j < 4; ++j)
                bfr[j] = *(const bf16x8*)&k_s[(wn * 64 + j * 16 + fr) * 72 + ks * 32 + fq * 8];
            #pragma unroll
            for (int i = 0; i < 4; ++i)
                #pragma unroll
                for (int j = 0; j < 4; ++j)
                    acc[i][j] = __builtin_amdgcn_mfma_f32_16x16x32_bf16(
                        af[i], bfr[j], acc[i][j], 0, 0, 0);
        }
        __syncthreads();   // BD tile visible

        // ---- score assembly (+BD shift, mask, scale) and row max ----
        const int Dl = j0 - i0;
        float rm[4][4];
        #pragma unroll
        for (int i = 0; i < 4; ++i)
            #pragma unroll
            for (int r = 0; r < 4; ++r) rm[i][r] = -3e38f;
        #pragma unroll
        for (int i = 0; i < 4; ++i) {
            #pragma unroll
            for (int r = 0; r < 4; ++r) {
                int ii = wm * 64 + i * 16 + fq * 4 + r;
                #pragma unroll
                for (int j = 0; j < 4; ++j) {
                    int jj = wn * 64 + j * 16 + fr;
                    int d = jj - ii;
                    int idx = 127 + d;
                    u16 bv = (idx < 128) ? bda[ii * 136 + idx] : bdb[ii * 136 + idx - 128];
                    float sv = (acc[i][j][r] + bf2f(bv)) * 0.125f;
                    sv = (Dl + d > 512) ? -1e30f : sv;
                    acc[i][j][r] = sv;
                    rm[i][r] = fmaxf(rm[i][r], sv);
                }
            }
        }
        #pragma unroll
        for (int i = 0; i < 4; ++i)
            #pragma unroll
            for (int r = 0; r < 4; ++r) {
                float v = rm[i][r];
                v = fmaxf(v, __shfl_xor(v, 1, 64));
                v = fmaxf(v, __shfl_xor(v, 2, 64));
                v = fmaxf(v, __shfl_xor(v, 4, 64));
                v = fmaxf(v, __shfl_xor(v, 8, 64));
                rm[i][r] = v;
            }
        if (fr == 0) {
            #pragma unroll
            for (int i = 0; i < 4; ++i)
                #pragma unroll
                for (int r = 0; r < 4; ++r)
                    pmax[wn][wm * 64 + i * 16 + fq * 4 + r] = rm[i][r];
        }
        __syncthreads();

        // ---- online softmax: m/alpha, P -> LDS, partial sums, O rescale ----
        float alpha[4][4];
        #pragma unroll
        for (int i = 0; i < 4; ++i)
            #pragma unroll
            for (int r = 0; r < 4; ++r) {
                int row = wm * 64 + i * 16 + fq * 4 + r;
                float tm = fmaxf(pmax[0][row], pmax[1][row]);
                float mn = fmaxf(m_st[i][r], tm);
                alpha[i][r] = __expf(m_st[i][r] - mn);
                m_st[i][r] = mn;
            }
        u16* Pp = bda;   // BDa slot is dead now; becomes P
        float rs[4][4];
        #pragma unroll
        for (int i = 0; i < 4; ++i)
            #pragma unroll
            for (int r = 0; r < 4; ++r) rs[i][r] = 0.f;
        #pragma unroll
        for (int i = 0; i < 4; ++i) {
            #pragma unroll
            for (int r = 0; r < 4; ++r) {
                int row = wm * 64 + i * 16 + fq * 4 + r;
                #pragma unroll
                for (int j = 0; j < 4; ++j) {
                    float p = __expf(acc[i][j][r] - m_st[i][r]);
                    rs[i][r] += p;
                    Pp[row * 136 + wn * 64 + j * 16 + fr] = f2bf(p);
                }
            }
        }
        #pragma unroll
        for (int i = 0; i < 4; ++i)
            #pragma unroll
            for (int r = 0; r < 4; ++r) {
                float v = rs[i][r];
                v += __shfl_xor(v, 1, 64);
                v += __shfl_xor(v, 2, 64);
                v += __shfl_xor(v, 4, 64);
                v += __shfl_xor(v, 8, 64);
                rs[i][r] = v;
            }
        if (fr == 0) {
            #pragma unroll
            for (int i = 0; i < 4; ++i)
                #pragma unroll
                for (int r = 0; r < 4; ++r)
                    psum[wn][wm * 64 + i * 16 + fq * 4 + r] = rs[i][r];
        }
        #pragma unroll
        for (int i = 0; i < 4; ++i)
            #pragma unroll
            for (int j = 0; j < 2; ++j)
                #pragma unroll
                for (int r = 0; r < 4; ++r) Oa[i][j][r] *= alpha[i][r];
        __syncthreads();

        // ---- l update + PV MFMA ----
        #pragma unroll
        for (int i = 0; i < 4; ++i)
            #pragma unroll
            for (int r = 0; r < 4; ++r) {
                int row = wm * 64 + i * 16 + fq * 4 + r;
                l_st[i][r] = alpha[i][r] * l_st[i][r] + psum[0][row] + psum[1][row];
            }
        #pragma unroll
        for (int ks = 0; ks < 4; ++ks) {
            bf16x8 pa[4], vb[2];
            #pragma unroll
            for (int i = 0; i < 4; ++i)
                pa[i] = *(const bf16x8*)&Pp[(wm * 64 + i * 16 + fr) * 136 + ks * 32 + fq * 8];
            #pragma unroll
            for (int j = 0; j < 2; ++j)
                vb[j] = *(const bf16x8*)&vT_s[(wn * 32 + j * 16 + fr) * 136 + ks * 32 + fq * 8];
            #pragma unroll
            for (int i = 0; i < 4; ++i)
                #pragma unroll
                for (int j = 0; j < 2; ++j)
                    Oa[i][j] = __builtin_amdgcn_mfma_f32_16x16x32_bf16(
                        pa[i], vb[j], Oa[i][j], 0, 0, 0);
        }
    }

    // ---- epilogue: O /= l, write attn_vec (i,b, n*64+d) bf16 ----
    #pragma unroll
    for (int i = 0; i < 4; ++i) {
        #pragma unroll
        for (int r = 0; r < 4; ++r) {
            int gi = i0 + wm * 64 + i * 16 + fq * 4 + r;
            float inv = 1.0f / l_st[i][r];
            #pragma unroll
            for (int j = 0; j < 2; ++j) {
                int col = n * 64 + wn * 32 + j * 16 + fr;
                attnv[((long)gi * 4 + b) * 1024 + col] = f2bf(Oa[i][j][r] * inv);
            }
        }
    }
}

// ---------------------------------------------------------------------------

__device__ __forceinline__ float blk_sum(float v, float* smv) {
    #pragma unroll
    for (int m = 32; m; m >>= 1) v += __shfl_xor(v, m, 64);
    int lane = threadIdx.x & 63, w = threadIdx.x >> 6;
    if (lane == 0) smv[w] = v;
    __syncthreads();
    v = smv[0] + smv[1] + smv[2] + smv[3];
    __syncthreads();
    return v;
}

__device__ __forceinline__ float blk_max(float v, float* smv) {
    #pragma unroll
    for (int m = 32; m; m >>= 1) v = fmaxf(v, __shfl_xor(v, m, 64));
    int lane = threadIdx.x & 63, w = threadIdx.x >> 6;
    if (lane == 0) smv[w] = v;
    __syncthreads();
    v = fmaxf(fmaxf(smv[0], smv[1]), fmaxf(smv[2], smv[3]));
    __syncthreads();
    return v;
}

__global__ __launch_bounds__(256)
void f2b_kernel(const float* __restrict__ in, u16* __restrict__ out, int n4)
{
    int i = blockIdx.x * 256 + threadIdx.x;
    if (i >= n4) return;
    float4 v = ((const float4*)in)[i];
    uint2 o;
    o.x = (unsigned)f2bf(v.x) | ((unsigned)f2bf(v.y) << 16);
    o.y = (unsigned)f2bf(v.z) | ((unsigned)f2bf(v.w) << 16);
    ((uint2*)out)[i] = o;
}

__global__ __launch_bounds__(256)
void cat_kernel(const float* __restrict__ memsl, const float* __restrict__ h,
                u16* __restrict__ cat)
{
    int i = blockIdx.x * 256 + threadIdx.x;
    float4 v = (i < 524288) ? ((const float4*)memsl)[i]
                            : ((const float4*)h)[i - 524288];
    uint2 o;
    o.x = (unsigned)f2bf(v.x) | ((unsigned)f2bf(v.y) << 16);
    o.y = (unsigned)f2bf(v.z) | ((unsigned)f2bf(v.w) << 16);
    ((uint2*)cat)[i] = o;
}

__global__ __launch_bounds__(256)
void embed_kernel(const int* __restrict__ data, const float* __restrict__ emb,
                  float* __restrict__ h)
{
    long idx = (long)blockIdx.x * 256 + threadIdx.x;
    int r = (int)(idx >> 10), d = (int)(idx & 1023);
    h[idx] = emb[(long)data[r] * 1024 + d] * 32.0f;
}

__global__ __launch_bounds__(256)
void posemb_kernel(u16* __restrict__ pe)
{
    int idx = blockIdx.x * 256 + threadIdx.x;
    int p = idx >> 10, d = idx & 1023;
    float pos = (float)(1023 - p);
    int j = d & 511;
    float invf = powf(10000.0f, -(float)j * (1.0f / 512.0f));
    float a = pos * invf;
    pe[idx] = f2bf((d < 512) ? sinf(a) : cosf(a));
}

__global__ __launch_bounds__(256)
void qwqr_kernel(const u16* __restrict__ heads, const float* __restrict__ rwb,
                 const float* __restrict__ rrb, u16* __restrict__ qw,
                 u16* __restrict__ qr)
{
    int idx = blockIdx.x * 256 + threadIdx.x;
    int d = idx & 63, i = (idx >> 6) & 511, n = (idx >> 15) & 15, b = idx >> 19;
    float v = bf2f(heads[(long)((512 + i) * 4 + b) * 3072 + n * 64 + d]);
    int e = n * 64 + d;
    qw[idx] = f2bf(v + rwb[e]);
    qr[idx] = f2bf(v + rrb[e]);
}

__global__ __launch_bounds__(256)
void add_ln_kernel(float* __restrict__ h, const float* __restrict__ res,
                   const float* __restrict__ g, const float* __restrict__ be)
{
    __shared__ float smv[4];
    int row = blockIdx.x, t = threadIdx.x;
    float* hp = h + (long)row * 1024;
    float4 x = *(float4*)(hp + t * 4);
    float4 rv = *(const float4*)(res + (long)row * 1024 + t * 4);
    x.x += rv.x; x.y += rv.y; x.z += rv.z; x.w += rv.w;
    float s = blk_sum(x.x + x.y + x.z + x.w, smv);
    float mu = s * (1.0f / 1024.0f);
    float d0 = x.x - mu, d1 = x.y - mu, d2 = x.z - mu, d3 = x.w - mu;
    float s2 = blk_sum(d0 * d0 + d1 * d1 + d2 * d2 + d3 * d3, smv);
    float inv = rsqrtf(s2 * (1.0f / 1024.0f) + 1e-5f);
    float4 gg = *(const float4*)(g + t * 4);
    float4 bb = *(const float4*)(be + t * 4);
    float4 o;
    o.x = d0 * inv * gg.x + bb.x;
    o.y = d1 * inv * gg.y + bb.y;
    o.z = d2 * inv * gg.z + bb.z;
    o.w = d3 * inv * gg.w + bb.w;
    *(float4*)(hp + t * 4) = o;
}

// merge 250 per-colblock (max, sumexp) partials into ms[row] = (m, s)
__global__ __launch_bounds__(256)
void lse_kernel(const float2* __restrict__ part, int nblk, float2* __restrict__ ms)
{
    __shared__ float smv[4];
    int row = blockIdx.x, t = threadIdx.x;
    const float2* pp = part + (long)row * nblk;
    float m = -3e38f;
    for (int j = t; j < nblk; j += 256) m = fmaxf(m, pp[j].x);
    m = blk_max(m, smv);
    float s = 0.f;
    for (int j = t; j < nblk; j += 256) {
        float2 p = pp[j];
        s += p.y * __expf(p.x - m);
    }
    s = blk_sum(s, smv);
    if (t == 0) ms[row] = make_float2(m, s);
}

__global__ __launch_bounds__(256)
void final_kernel(const float* __restrict__ h, const float* __restrict__ emb,
                  const float* __restrict__ ob, const int* __restrict__ target,
                  const float2* __restrict__ ms, float* __restrict__ out)
{
    __shared__ float smv[4];
    int row = blockIdx.x, t = threadIdx.x;
    int tok = target[row];
    const float* hp = h + (long)row * 1024;
    const float* ep = emb + (long)tok * 1024;
    float4 a = *(const float4*)(hp + t * 4);
    float4 b = *(const float4*)(ep + t * 4);
    float s = blk_sum(a.x * b.x + a.y * b.y + a.z * b.z + a.w * b.w, smv);
    if (t == 0) {
        float2 v = ms[row];
        out[row] = v.x + logf(v.y) - (s + ob[tok]);
    }
}

// ---------------------------------------------------------------------------

extern "C" void kernel_launch(void* const* d_in, const int* in_sizes, int n_in,
                              void* d_out, int out_size, void* d_ws, size_t ws_size,
                              hipStream_t stream)
{
    const int*   data     = (const int*)d_in[0];
    const int*   target   = (const int*)d_in[1];
    const float* mems     = (const float*)d_in[2];
    const float* emb      = (const float*)d_in[3];
    const float* out_bias = (const float*)d_in[4];
    const float* r_w_bias = (const float*)d_in[5];
    const float* r_r_bias = (const float*)d_in[6];
    const float* qkv_w    = (const float*)d_in[7];
    const float* r_w      = (const float*)d_in[8];
    const float* o_w      = (const float*)d_in[9];
    const float* ln1_g    = (const float*)d_in[10];
    const float* ln1_b    = (const float*)d_in[11];
    const float* ff1_w    = (const float*)d_in[12];
    const float* ff1_b    = (const float*)d_in[13];
    const float* ff2_w    = (const float*)d_in[14];
    const float* ff2_b    = (const float*)d_in[15];
    const float* ln2_g    = (const float*)d_in[16];
    const float* ln2_b    = (const float*)d_in[17];
    float* out = (float*)d_out;
    float* ws  = (float*)d_ws;

    // workspace layout (float offsets)
    float* h       = ws;                            // 2,097,152 f
    float* tmp     = ws + 2097152;                  // 2,097,152 f
    u16*  pe_bf    = (u16*)(ws + 4194304);          // 1M bf16
    u16*  rbuf_bf  = (u16*)(ws + 4718592);          // 1M bf16
    u16*  cat_bf   = (u16*)(ws + 5242880);          // 4M bf16
    u16*  heads_bf = (u16*)(ws + 7340032);          // 12.58M bf16
    u16*  qw_bf    = (u16*)(ws + 13631488);         // 2M bf16
    u16*  qr_bf    = (u16*)(ws + 14680064);         // 2M bf16
    u16*  attnv_bf = (u16*)(ws + 15728640);         // 2M bf16
    u16*  h_bf     = (u16*)(ws + 16777216);         // 1M bf16
    u16*  wqkv     = (u16*)(ws + 17825792);         // 3.15M bf16
    u16*  wr       = wqkv + 3145728;
    u16*  wo       = wr + 1048576;
    u16*  wf1      = wo + 1048576;
    u16*  wf2      = wf1 + 4194304;                 // ends at 24641536 f
    float* big     = ws + 24641536;                 // 33,554,432 f scratch
    float2* ms     = (float2*)(ws + 58195968);      // 2048 float2
    u16*  ffh_bf   = (u16*)big;                     // 2048x4096 bf16 (layer phase)
    u16*  embc_bf  = (u16*)big;                     // 32000x1024 bf16 (final phase)
    float2* partials = (float2*)(big + 16777216);   // 2048 x 250 float2 (final phase)

    embed_kernel<<<8192, 256, 0, stream>>>(data, emb, h);
    posemb_kernel<<<4096, 256, 0, stream>>>(pe_bf);

    for (int l = 0; l < 6; ++l) {
        f2b_kernel<<<3072, 256, 0, stream>>>(qkv_w + (size_t)l * 3145728, wqkv, 786432);
        f2b_kernel<<<1024, 256, 0, stream>>>(r_w + (size_t)l * 1048576, wr, 262144);
        f2b_kernel<<<1024, 256, 0, stream>>>(o_w + (size_t)l * 1048576, wo, 262144);
        f2b_kernel<<<4096, 256, 0, stream>>>(ff1_w + (size_t)l * 4194304, wf1, 1048576);
        f2b_kernel<<<4096, 256, 0, stream>>>(ff2_w + (size_t)l * 4194304, wf2, 1048576);
        cat_kernel<<<4096, 256, 0, stream>>>(mems + (size_t)l * 2097152, h, cat_bf);

        // heads = cat @ qkv^T        (4096,3072,1024)
        mg<128,128,1>(stream, cat_bf, 1024, 0, 0, LINMOD, wqkv, 1024, 0, 0, LINMOD,
                      heads_bf, 3072, 0, 0, LINMOD, nullptr, 4096, 3072, 1024, 0, 1, 1);
        // rbuf = pos_emb @ r_w^T     (1024,1024,1024)
        mg<64,64,1>(stream, pe_bf, 1024, 0, 0, LINMOD, wr, 1024, 0, 0, LINMOD,
                    rbuf_bf, 1024, 0, 0, LINMOD, nullptr, 1024, 1024, 1024, 0, 1, 0);

        qwqr_kernel<<<8192, 256, 0, stream>>>(heads_bf, r_w_bias, r_r_bias, qw_bf, qr_bf);

        // fused rel-attention -> attn_vec (bf16)
        attn_kernel<<<dim3(64, 4), 256, 0, stream>>>(qw_bf, qr_bf, heads_bf,
                                                     rbuf_bf, attnv_bf);

        // attn_out = attn_vec @ o_w^T (2048,1024,1024) — 128x64 tile: 256 blocks
        mg<128,64,0>(stream, attnv_bf, 1024, 0, 0, LINMOD, wo, 1024, 0, 0, LINMOD,
                     tmp, 1024, 0, 0, LINMOD, nullptr, 2048, 1024, 1024, 0, 1, 1);

        add_ln_kernel<<<2048, 256, 0, stream>>>(h, tmp, ln1_g + l * 1024, ln1_b + l * 1024);
        f2b_kernel<<<2048, 256, 0, stream>>>(h, h_bf, 524288);

        // ffh = relu(h @ ff1^T + b1)  (2048,4096,1024) — 128x128 tile: 512 blocks
        mg<128,128,1>(stream, h_bf, 1024, 0, 0, LINMOD, wf1, 1024, 0, 0, LINMOD,
                      ffh_bf, 4096, 0, 0, LINMOD, ff1_b + l * 4096, 2048, 4096, 1024, 1, 1, 1);
        // ffo = ffh @ ff2^T + b2      (2048,1024,4096) — 128x64 tile: 256 blocks
        mg<128,64,0>(stream, ffh_bf, 4096, 0, 0, LINMOD, wf2, 4096, 0, 0, LINMOD,
                     tmp, 1024, 0, 0, LINMOD, ff2_b + l * 1024, 2048, 1024, 4096, 0, 1, 1);

        add_ln_kernel<<<2048, 256, 0, stream>>>(h, tmp, ln2_g + l * 1024, ln2_b + l * 1024);
    }

    f2b_kernel<<<2048, 256, 0, stream>>>(h, h_bf, 524288);
    // full-vocab bf16 conversion of emb (32000x1024)
    f2b_kernel<<<32000, 256, 0, stream>>>(emb, embc_bf, 8192000);

    // logits GEMM with fused per-tile logsumexp reduction (no logits stored):
    // grid (32000/128=250, 2048/128=16), partials[row][colblk] = (max, sumexp)
    mg<128,128,2>(stream, h_bf, 1024, 0, 0, LINMOD, embc_bf, 1024, 0, 0, LINMOD,
                  partials, 0, 0, 0, LINMOD, out_bias, 2048, 32000, 1024, 0, 1, 1);

    lse_kernel<<<2048, 256, 0, stream>>>(partials, 250, ms);
    final_kernel<<<2048, 256, 0, stream>>>(h, emb, out_bias, target, ms, out);
}